// Round 21
// baseline (31.073 us; speedup 1.0000x reference)
//
#include <hip/hip_runtime.h>

#define NN 160      // nodes
#define BB 128      // batch
#define HH 256      // hidden
#define EE 5120     // edges
#define ST 128      // state dim
#define AC 32       // action dim
#define IH 80       // i-half rows

typedef __attribute__((ext_vector_type(8))) short short8;
typedef __attribute__((ext_vector_type(4))) short bf16x4;
typedef unsigned short us;
typedef __attribute__((ext_vector_type(4))) float f32x4;

__device__ inline us f2b(float f) {
    unsigned u = __builtin_bit_cast(unsigned, f);
    unsigned r = (u + 0x7FFFu + ((u >> 16) & 1u)) >> 16;
    return (us)r;
}
__device__ inline float b2f(us h) {
    return __builtin_bit_cast(float, (unsigned)h << 16);
}

// ---------- K1: graph rows + Pb/Mb (int-exact) + weight transposes + out init ----------
__global__ __launch_bounds__(256)
void k_pre(const int* __restrict__ ei, const float* __restrict__ W1,
           const float* __restrict__ W2, const float* __restrict__ state,
           const float* __restrict__ bo, us* __restrict__ Pb,
           us* __restrict__ Mb, us* __restrict__ W1t, us* __restrict__ W2t,
           float* __restrict__ out)
{
    const int bx = blockIdx.x, tid = threadIdx.x;
    if (bx < NN) {
        __shared__ int crow[NN];
        __shared__ unsigned abit[NN * NN / 32];   // 3.2 KB
        __shared__ float invdeg;
        if (tid < NN) crow[tid] = 0;
        for (int i = tid; i < NN * NN / 32; i += 256) abit[i] = 0;
        __syncthreads();
        for (int e = tid; e < EE; e += 256) {
            int s = ei[e], d = ei[EE + e];
            int p = d * NN + s;
            atomicOr(&abit[p >> 5], 1u << (p & 31));
            if (d == bx) atomicAdd(&crow[s], 1);
        }
        if (tid < NN) {
            int p = tid * NN + tid;
            atomicOr(&abit[p >> 5], 1u << (p & 31));
        }
        __syncthreads();
        if (tid == 0) {
            int dg = 0;
            for (int j = 0; j < NN; j++) dg += crow[j];
            invdeg = 1.0f / (float)(dg < 1 ? 1 : dg);
        }
        __syncthreads();
        if (tid < NN) {
            int s = 0;
            for (int k = 0; k < NN; k++) {
                int p = k * NN + tid;
                if (abit[p >> 5] & (1u << (p & 31))) s += crow[k];
            }
            Pb[bx * NN + tid] = f2b((float)s * invdeg);
            Mb[bx * NN + tid] = f2b((float)crow[tid] * invdeg);
        }
    } else if (bx < NN + 160) {                   // W1t: 256x160
        int idx = (bx - NN) * 256 + tid;
        int n = idx / NN, k = idx - n * NN;
        W1t[idx] = f2b(W1[k * HH + n]);
    } else if (bx < NN + 160 + 256) {             // W2t: 256x256
        int idx = (bx - NN - 160) * 256 + tid;
        int n = idx >> 8, k = idx & 255;
        W2t[idx] = f2b(W2[k * HH + n]);
    } else {                                      // out init: 128x128
        int idx = (bx - NN - 160 - 256) * 256 + tid;
        out[idx] = state[idx] + bo[idx & 127];
    }
}

// ---------- K2: 256 blocks = (i-half, batch), 1024 threads (16 waves) ----------
// Reuse-matched placement: Ys (8x) + Mbs (16x) in LDS; W1t/W2t direct global.
// G1 retiled: wave (wh=w&7, wi=w>>3) owns 32h x 80i -> 5 LDS + 2 global reads
// per 10 MFMAs (halved G1 LDS traffic vs 1-col tiling).
__global__ __launch_bounds__(1024, 4)
void k_mega(const us* __restrict__ Pb, const float* __restrict__ state,
            const float* __restrict__ action, const us* __restrict__ W1t,
            const float* __restrict__ b1, const us* __restrict__ Mb,
            const us* __restrict__ W2t, const float* __restrict__ b2,
            const float* __restrict__ Wo, float* __restrict__ out)
{
    // SH regions (shorts):
    //  Ys  @0      [160][168] = 26880   (dead after B3)
    //    recycled: Mbs @0 [80][168]=13440 ; pp f32 @13440 ; pts f32 @15488
    //  h1s @26880  [256][168] = 43008   (dead after B5)
    //    recycled: ts @26880 [80][264] (extent 21112 <= 21120... fits in 43008)
    __shared__ __align__(16) us SH[69888];        // 139776 B
    __shared__ float xb[NN];
    us* Ys  = SH;
    us* h1s = SH + 26880;
    us* Mbs = SH;
    us* ts  = SH + 26880;
    float* pp  = (float*)&SH[13440];  // [4][256] f32
    float* pts = (float*)&SH[15488];  // [4][128] f32

    const int ihalf = blockIdx.x, b = blockIdx.y, i_base = ihalf * IH;
    const int tid = threadIdx.x, lane = tid & 63, w = tid >> 6;  // 16 waves
    const int rl = lane & 15, kq = lane >> 4;

    if (tid < NN) xb[tid] = (tid < ST) ? state[b * ST + tid]
                                       : action[b * AC + (tid - ST)];
    __syncthreads();                                           // B1: xb

    // ---- stage Y = bf16(Pb*x) once, resident ----
    for (int c = tid; c < 3200; c += 1024) {
        int r = c / 20, col = (c % 20) * 8;
        short8 p = *(const short8*)&Pb[r * NN + col];
        short8 y;
#pragma unroll
        for (int u = 0; u < 8; u++)
            y[u] = (short)f2b(b2f((us)p[u]) * xb[col + u]);
        *(short8*)&Ys[r * 168 + col] = y;
    }
    __syncthreads();                                           // B2: Ys

    // ======== G1, barrier-free, retiled 32h x 80i per wave ========
    // wave (wh = w&7, wi = w>>3): h in [32wh,32wh+32), i in [80wi,80wi+80)
    {
        const int wh = w & 7, wi = w >> 3;
        f32x4 acc1[5][2];
#pragma unroll
        for (int f = 0; f < 5; f++)
#pragma unroll
            for (int j = 0; j < 2; j++) acc1[f][j] = f32x4{0.f, 0.f, 0.f, 0.f};

        const us* w1r0 = W1t + (size_t)(wh * 32 + rl) * NN + kq * 8;
        const us* w1r1 = W1t + (size_t)(wh * 32 + 16 + rl) * NN + kq * 8;
#pragma unroll
        for (int kk = 0; kk < 5; kk++) {
            short8 bv0 = *(const short8*)&w1r0[kk * 32];
            short8 bv1 = *(const short8*)&w1r1[kk * 32];
            short8 af[5];
#pragma unroll
            for (int f = 0; f < 5; f++)
                af[f] = *(const short8*)&Ys[(wi * 80 + f * 16 + rl) * 168 + kk * 32 + kq * 8];
#pragma unroll
            for (int f = 0; f < 5; f++) {
                acc1[f][0] = __builtin_amdgcn_mfma_f32_16x16x32_bf16(
                    af[f], bv0, acc1[f][0], 0, 0, 0);
                acc1[f][1] = __builtin_amdgcn_mfma_f32_16x16x32_bf16(
                    af[f], bv1, acc1[f][1], 0, 0, 0);
            }
        }
        // epi: D[i][h]: col h = 32wh + j*16 + rl, rows i = 80wi + f*16 + kq*4 + r
#pragma unroll
        for (int j = 0; j < 2; j++) {
            int h = wh * 32 + j * 16 + rl;
            float bias = b1[h];
#pragma unroll
            for (int f = 0; f < 5; f++) {
                int i0 = wi * 80 + f * 16 + kq * 4;
                bf16x4 v;
#pragma unroll
                for (int r = 0; r < 4; r++) {
                    float t = acc1[f][j][r] + bias;
                    v[r] = (short)f2b(t > 0.f ? t : 0.f);
                }
                *(bf16x4*)&h1s[h * 168 + i0] = v;
            }
        }
    }
    __syncthreads();                        // B3: h1s complete; Ys dead

    // ---- stage Mbs (16x reuse) into dead Ys region ----
    for (int c = tid; c < 1600; c += 1024) {
        int r = c / 20, col = (c % 20) * 8;
        *(short8*)&Mbs[r * 168 + col] =
            *(const short8*)&Mb[(size_t)(i_base + r) * NN + col];
    }
    __syncthreads();                        // B4: Mbs ready

    // ======== G2 MFMAs, barrier-free (h1s + Mbs resident; acc in regs) ========
    f32x4 acc2[5];
#pragma unroll
    for (int j = 0; j < 5; j++) acc2[j] = f32x4{0.f, 0.f, 0.f, 0.f};
#pragma unroll
    for (int kk = 0; kk < 5; kk++) {
        short8 a = *(const short8*)&h1s[(w * 16 + rl) * 168 + kk * 32 + kq * 8];
        short8 bfv[5];
#pragma unroll
        for (int j = 0; j < 5; j++)
            bfv[j] = *(const short8*)&Mbs[(j * 16 + rl) * 168 + kk * 32 + kq * 8];
#pragma unroll
        for (int j = 0; j < 5; j++)
            acc2[j] = __builtin_amdgcn_mfma_f32_16x16x32_bf16(
                a, bfv[j], acc2[j], 0, 0, 0);
    }
    __syncthreads();                        // B5: h1s reads done -> ts overlay safe

    // ---- G2 epi: D[h][i']: 4 consec h per reg-quad -> packed ts[i'][h0..3] ----
    {
        int h0 = w * 16 + kq * 4;
#pragma unroll
        for (int j = 0; j < 5; j++) {
            int ip = j * 16 + rl;
            bf16x4 v;
#pragma unroll
            for (int r = 0; r < 4; r++)
                v[r] = (short)f2b(acc2[j][r]);
            *(bf16x4*)&ts[ip * 264 + h0] = v;
        }
    }
    __syncthreads();                        // B6: ts ready

    // ======== G3, barrier-free: A=ts (LDS), B=W2t (global, 1x) ========
    f32x4 acc3[5];
#pragma unroll
    for (int f = 0; f < 5; f++) acc3[f] = f32x4{0.f, 0.f, 0.f, 0.f};
    {
        const us* w2row = W2t + (size_t)(w * 16 + rl) * HH + kq * 8;
#pragma unroll
        for (int kk = 0; kk < 8; kk++) {
            short8 bv = *(const short8*)&w2row[kk * 32];
            short8 af[5];
#pragma unroll
            for (int f = 0; f < 5; f++)
                af[f] = *(const short8*)&ts[(f * 16 + rl) * 264 + kk * 32 + kq * 8];
#pragma unroll
            for (int f = 0; f < 5; f++)
                acc3[f] = __builtin_amdgcn_mfma_f32_16x16x32_bf16(
                    af[f], bv, acc3[f], 0, 0, 0);
        }
    }

    // ---- epi: bias+relu, in-lane pool over 20 i'-rows, slot by kq ----
    {
        int h = w * 16 + rl;
        float bias = b2[h];
        float s = 0.f;
#pragma unroll
        for (int f = 0; f < 5; f++)
#pragma unroll
            for (int r = 0; r < 4; r++) {
                float v = acc3[f][r] + bias;
                s += v > 0.f ? v : 0.f;
            }
        pp[kq * HH + h] = s;
    }
    __syncthreads();                        // B7: pp done
    // ---- head partial: out[b][s] += (sum_h ph[h]*Wo[h][s]) / NN ----
    {
        const int q8 = tid >> 7, s128 = tid & 127;   // 8 h-chunks of 32
        float part = 0.f;
        for (int hx = q8 * 32; hx < q8 * 32 + 32; hx++) {
            float ph = pp[0 * HH + hx] + pp[1 * HH + hx] +
                       pp[2 * HH + hx] + pp[3 * HH + hx];
            part += ph * Wo[hx * ST + s128];
        }
        if (q8 < 4) pts[q8 * ST + s128] = part;
        __syncthreads();                    // B8
        if (q8 >= 4) atomicAdd(&pts[(q8 - 4) * ST + s128], part);
        __syncthreads();                    // B9: pts done
        if (tid < ST) {
            float o = pts[0 * ST + tid] + pts[1 * ST + tid] +
                      pts[2 * ST + tid] + pts[3 * ST + tid];
            atomicAdd(&out[b * ST + tid], o * (1.0f / NN));
        }
    }
}

extern "C" void kernel_launch(void* const* d_in, const int* in_sizes, int n_in,
                              void* d_out, int out_size, void* d_ws, size_t ws_size,
                              hipStream_t stream) {
    const float* state  = (const float*)d_in[0];
    const float* action = (const float*)d_in[1];
    const int*   ei     = (const int*)d_in[2];
    const float* W1     = (const float*)d_in[3];
    const float* b1     = (const float*)d_in[4];
    const float* W2     = (const float*)d_in[5];
    const float* b2     = (const float*)d_in[6];
    const float* Wo     = (const float*)d_in[7];
    const float* bo     = (const float*)d_in[8];
    float* out = (float*)d_out;

    char* ws = (char*)d_ws;
    size_t off = 0;
    auto alloc = [&](size_t bytes) {
        void* p = ws + off;
        off += (bytes + 255) & ~(size_t)255;
        return p;
    };
    us* Pb  = (us*)alloc(NN * NN * 2);
    us* Mb  = (us*)alloc(NN * NN * 2);
    us* W1t = (us*)alloc((size_t)HH * NN * 2);
    us* W2t = (us*)alloc((size_t)HH * HH * 2);

    // 160 graph rows + 160 W1t blocks + 256 W2t blocks + 64 out-init blocks
    k_pre<<<NN + 160 + 256 + 64, 256, 0, stream>>>(ei, W1, W2, state, bo,
                                                   Pb, Mb, W1t, W2t, out);
    {
        dim3 g(2, BB);   // (i-half, batch) = 256 blocks
        k_mega<<<g, 1024, 0, stream>>>(Pb, state, action, W1t, b1, Mb, W2t, b2,
                                       Wo, out);
    }
}

// Round 22
// 30.977 us; speedup vs baseline: 1.0031x; 1.0031x over previous
//
#include <hip/hip_runtime.h>

#define NN 160      // nodes
#define BB 128      // batch
#define HH 256      // hidden
#define EE 5120     // edges
#define ST 128      // state dim
#define AC 32       // action dim
#define IH 80       // i-half rows

typedef __attribute__((ext_vector_type(8))) short short8;
typedef __attribute__((ext_vector_type(4))) short bf16x4;
typedef unsigned short us;
typedef __attribute__((ext_vector_type(4))) float f32x4;

__device__ inline us f2b(float f) {
    unsigned u = __builtin_bit_cast(unsigned, f);
    unsigned r = (u + 0x7FFFu + ((u >> 16) & 1u)) >> 16;
    return (us)r;
}
__device__ inline float b2f(us h) {
    return __builtin_bit_cast(float, (unsigned)h << 16);
}

// ---------- K1: graph rows + Pb/Mb (int-exact) + weight transposes + out init ----------
__global__ __launch_bounds__(256)
void k_pre(const int* __restrict__ ei, const float* __restrict__ W1,
           const float* __restrict__ W2, const float* __restrict__ state,
           const float* __restrict__ bo, us* __restrict__ Pb,
           us* __restrict__ Mb, us* __restrict__ W1t, us* __restrict__ W2t,
           float* __restrict__ out)
{
    const int bx = blockIdx.x, tid = threadIdx.x;
    if (bx < NN) {
        __shared__ int crow[NN];
        __shared__ unsigned abit[NN * NN / 32];   // 3.2 KB
        __shared__ float invdeg;
        if (tid < NN) crow[tid] = 0;
        for (int i = tid; i < NN * NN / 32; i += 256) abit[i] = 0;
        __syncthreads();
        for (int e = tid; e < EE; e += 256) {
            int s = ei[e], d = ei[EE + e];
            int p = d * NN + s;
            atomicOr(&abit[p >> 5], 1u << (p & 31));
            if (d == bx) atomicAdd(&crow[s], 1);
        }
        if (tid < NN) {
            int p = tid * NN + tid;
            atomicOr(&abit[p >> 5], 1u << (p & 31));
        }
        __syncthreads();
        if (tid == 0) {
            int dg = 0;
            for (int j = 0; j < NN; j++) dg += crow[j];
            invdeg = 1.0f / (float)(dg < 1 ? 1 : dg);
        }
        __syncthreads();
        if (tid < NN) {
            int s = 0;
            for (int k = 0; k < NN; k++) {
                int p = k * NN + tid;
                if (abit[p >> 5] & (1u << (p & 31))) s += crow[k];
            }
            Pb[bx * NN + tid] = f2b((float)s * invdeg);
            Mb[bx * NN + tid] = f2b((float)crow[tid] * invdeg);
        }
    } else if (bx < NN + 160) {                   // W1t: 256x160
        int idx = (bx - NN) * 256 + tid;
        int n = idx / NN, k = idx - n * NN;
        W1t[idx] = f2b(W1[k * HH + n]);
    } else if (bx < NN + 160 + 256) {             // W2t: 256x256
        int idx = (bx - NN - 160) * 256 + tid;
        int n = idx >> 8, k = idx & 255;
        W2t[idx] = f2b(W2[k * HH + n]);
    } else {                                      // out init: 128x128
        int idx = (bx - NN - 160 - 256) * 256 + tid;
        out[idx] = state[idx] + bo[idx & 127];
    }
}

// ---------- K2: 256 blocks = (i-half, batch), 1024 threads (16 waves) ----------
// Reuse-matched placement: Ys (8x) + Mbs (16x) in LDS; W1t/W2t direct global.
// T14: Mb chunk loads issued BEFORE G1 (latency hidden under G1 MFMAs);
// LDS writes after B3. Head reduction slotted (no LDS atomics). 8 barriers.
__global__ __launch_bounds__(1024, 4)
void k_mega(const us* __restrict__ Pb, const float* __restrict__ state,
            const float* __restrict__ action, const us* __restrict__ W1t,
            const float* __restrict__ b1, const us* __restrict__ Mb,
            const us* __restrict__ W2t, const float* __restrict__ b2,
            const float* __restrict__ Wo, float* __restrict__ out)
{
    // SH regions (shorts):
    //  Ys  @0      [160][168] = 26880  (dead after B3)
    //    recycled: Mbs @0 [80][168]=13440 ; pp f32 @13440 (2048 sh);
    //              pts f32 @15488 [8][128] (2048 sh -> 17536 < 26880)
    //  h1s @26880  [256][168] = 43008  (dead after B5)
    //    recycled: ts @26880 [80][264] (extent 21112 <= 43008)
    __shared__ __align__(16) us SH[69888];        // 139776 B
    __shared__ float xb[NN];
    us* Ys  = SH;
    us* h1s = SH + 26880;
    us* Mbs = SH;
    us* ts  = SH + 26880;
    float* pp  = (float*)&SH[13440];  // [4][256] f32
    float* pts = (float*)&SH[15488];  // [8][128] f32

    const int ihalf = blockIdx.x, b = blockIdx.y, i_base = ihalf * IH;
    const int tid = threadIdx.x, lane = tid & 63, w = tid >> 6;  // 16 waves
    const int rl = lane & 15, kq = lane >> 4;

    if (tid < NN) xb[tid] = (tid < ST) ? state[b * ST + tid]
                                       : action[b * AC + (tid - ST)];
    __syncthreads();                                           // B1: xb

    // ---- stage Y = bf16(Pb*x) once, resident ----
    for (int c = tid; c < 3200; c += 1024) {
        int r = c / 20, col = (c % 20) * 8;
        short8 p = *(const short8*)&Pb[r * NN + col];
        short8 y;
#pragma unroll
        for (int u = 0; u < 8; u++)
            y[u] = (short)f2b(b2f((us)p[u]) * xb[col + u]);
        *(short8*)&Ys[r * 168 + col] = y;
    }
    __syncthreads();                                           // B2: Ys

    // ---- T14: issue Mb chunk loads NOW (latency hides under G1) ----
    // 1600 chunks over 1024 threads: chunk tid (all), chunk tid+1024 (tid<576)
    short8 mb0, mb1;
    {
        int c0 = tid;
        int r0 = c0 / 20, col0 = (c0 % 20) * 8;
        mb0 = *(const short8*)&Mb[(size_t)(i_base + r0) * NN + col0];
        if (tid < 576) {
            int c1 = tid + 1024;
            int r1 = c1 / 20, col1 = (c1 % 20) * 8;
            mb1 = *(const short8*)&Mb[(size_t)(i_base + r1) * NN + col1];
        }
    }

    // ======== G1, barrier-free, 32h x 80i per wave ========
    {
        const int wh = w & 7, wi = w >> 3;
        f32x4 acc1[5][2];
#pragma unroll
        for (int f = 0; f < 5; f++)
#pragma unroll
            for (int j = 0; j < 2; j++) acc1[f][j] = f32x4{0.f, 0.f, 0.f, 0.f};

        const us* w1r0 = W1t + (size_t)(wh * 32 + rl) * NN + kq * 8;
        const us* w1r1 = W1t + (size_t)(wh * 32 + 16 + rl) * NN + kq * 8;
#pragma unroll
        for (int kk = 0; kk < 5; kk++) {
            short8 bv0 = *(const short8*)&w1r0[kk * 32];
            short8 bv1 = *(const short8*)&w1r1[kk * 32];
            short8 af[5];
#pragma unroll
            for (int f = 0; f < 5; f++)
                af[f] = *(const short8*)&Ys[(wi * 80 + f * 16 + rl) * 168 + kk * 32 + kq * 8];
#pragma unroll
            for (int f = 0; f < 5; f++) {
                acc1[f][0] = __builtin_amdgcn_mfma_f32_16x16x32_bf16(
                    af[f], bv0, acc1[f][0], 0, 0, 0);
                acc1[f][1] = __builtin_amdgcn_mfma_f32_16x16x32_bf16(
                    af[f], bv1, acc1[f][1], 0, 0, 0);
            }
        }
        // epi: D[i][h]: col h = 32wh + j*16 + rl, rows i = 80wi + f*16 + kq*4 + r
#pragma unroll
        for (int j = 0; j < 2; j++) {
            int h = wh * 32 + j * 16 + rl;
            float bias = b1[h];
#pragma unroll
            for (int f = 0; f < 5; f++) {
                int i0 = wi * 80 + f * 16 + kq * 4;
                bf16x4 v;
#pragma unroll
                for (int r = 0; r < 4; r++) {
                    float t = acc1[f][j][r] + bias;
                    v[r] = (short)f2b(t > 0.f ? t : 0.f);
                }
                *(bf16x4*)&h1s[h * 168 + i0] = v;
            }
        }
    }
    __syncthreads();                        // B3: h1s complete; Ys dead

    // ---- write pre-loaded Mb chunks into dead Ys region ----
    {
        int c0 = tid;
        int r0 = c0 / 20, col0 = (c0 % 20) * 8;
        *(short8*)&Mbs[r0 * 168 + col0] = mb0;
        if (tid < 576) {
            int c1 = tid + 1024;
            int r1 = c1 / 20, col1 = (c1 % 20) * 8;
            *(short8*)&Mbs[r1 * 168 + col1] = mb1;
        }
    }
    __syncthreads();                        // B4: Mbs ready

    // ======== G2 MFMAs, barrier-free (h1s + Mbs resident) ========
    f32x4 acc2[5];
#pragma unroll
    for (int j = 0; j < 5; j++) acc2[j] = f32x4{0.f, 0.f, 0.f, 0.f};
#pragma unroll
    for (int kk = 0; kk < 5; kk++) {
        short8 a = *(const short8*)&h1s[(w * 16 + rl) * 168 + kk * 32 + kq * 8];
        short8 bfv[5];
#pragma unroll
        for (int j = 0; j < 5; j++)
            bfv[j] = *(const short8*)&Mbs[(j * 16 + rl) * 168 + kk * 32 + kq * 8];
#pragma unroll
        for (int j = 0; j < 5; j++)
            acc2[j] = __builtin_amdgcn_mfma_f32_16x16x32_bf16(
                a, bfv[j], acc2[j], 0, 0, 0);
    }
    __syncthreads();                        // B5: h1s reads done -> ts overlay safe

    // ---- G2 epi: D[h][i']: 4 consec h per reg-quad -> packed ts[i'][h0..3] ----
    {
        int h0 = w * 16 + kq * 4;
#pragma unroll
        for (int j = 0; j < 5; j++) {
            int ip = j * 16 + rl;
            bf16x4 v;
#pragma unroll
            for (int r = 0; r < 4; r++)
                v[r] = (short)f2b(acc2[j][r]);
            *(bf16x4*)&ts[ip * 264 + h0] = v;
        }
    }
    __syncthreads();                        // B6: ts ready

    // ======== G3, barrier-free: A=ts (LDS), B=W2t (global, 1x) ========
    f32x4 acc3[5];
#pragma unroll
    for (int f = 0; f < 5; f++) acc3[f] = f32x4{0.f, 0.f, 0.f, 0.f};
    {
        const us* w2row = W2t + (size_t)(w * 16 + rl) * HH + kq * 8;
#pragma unroll
        for (int kk = 0; kk < 8; kk++) {
            short8 bv = *(const short8*)&w2row[kk * 32];
            short8 af[5];
#pragma unroll
            for (int f = 0; f < 5; f++)
                af[f] = *(const short8*)&ts[(f * 16 + rl) * 264 + kk * 32 + kq * 8];
#pragma unroll
            for (int f = 0; f < 5; f++)
                acc3[f] = __builtin_amdgcn_mfma_f32_16x16x32_bf16(
                    af[f], bv, acc3[f], 0, 0, 0);
        }
    }

    // ---- epi: bias+relu, in-lane pool over 20 i'-rows, slot by kq ----
    {
        int h = w * 16 + rl;
        float bias = b2[h];
        float s = 0.f;
#pragma unroll
        for (int f = 0; f < 5; f++)
#pragma unroll
            for (int r = 0; r < 4; r++) {
                float v = acc3[f][r] + bias;
                s += v > 0.f ? v : 0.f;
            }
        pp[kq * HH + h] = s;
    }
    __syncthreads();                        // B7: pp done
    // ---- head partial: out[b][s] += (sum_h ph[h]*Wo[h][s]) / NN ----
    {
        const int q8 = tid >> 7, s128 = tid & 127;   // 8 h-chunks of 32
        float part = 0.f;
        for (int hx = q8 * 32; hx < q8 * 32 + 32; hx++) {
            float ph = pp[0 * HH + hx] + pp[1 * HH + hx] +
                       pp[2 * HH + hx] + pp[3 * HH + hx];
            part += ph * Wo[hx * ST + s128];
        }
        pts[q8 * ST + s128] = part;
        __syncthreads();                    // B8: pts done
        if (tid < ST) {
            float o = 0.f;
#pragma unroll
            for (int qq = 0; qq < 8; qq++) o += pts[qq * ST + tid];
            atomicAdd(&out[b * ST + tid], o * (1.0f / NN));
        }
    }
}

extern "C" void kernel_launch(void* const* d_in, const int* in_sizes, int n_in,
                              void* d_out, int out_size, void* d_ws, size_t ws_size,
                              hipStream_t stream) {
    const float* state  = (const float*)d_in[0];
    const float* action = (const float*)d_in[1];
    const int*   ei     = (const int*)d_in[2];
    const float* W1     = (const float*)d_in[3];
    const float* b1     = (const float*)d_in[4];
    const float* W2     = (const float*)d_in[5];
    const float* b2     = (const float*)d_in[6];
    const float* Wo     = (const float*)d_in[7];
    const float* bo     = (const float*)d_in[8];
    float* out = (float*)d_out;

    char* ws = (char*)d_ws;
    size_t off = 0;
    auto alloc = [&](size_t bytes) {
        void* p = ws + off;
        off += (bytes + 255) & ~(size_t)255;
        return p;
    };
    us* Pb  = (us*)alloc(NN * NN * 2);
    us* Mb  = (us*)alloc(NN * NN * 2);
    us* W1t = (us*)alloc((size_t)HH * NN * 2);
    us* W2t = (us*)alloc((size_t)HH * HH * 2);

    // 160 graph rows + 160 W1t blocks + 256 W2t blocks + 64 out-init blocks
    k_pre<<<NN + 160 + 256 + 64, 256, 0, stream>>>(ei, W1, W2, state, bo,
                                                   Pb, Mb, W1t, W2t, out);
    {
        dim3 g(2, BB);   // (i-half, batch) = 256 blocks
        k_mega<<<g, 1024, 0, stream>>>(Pb, state, action, W1t, b1, Mb, W2t, b2,
                                       Wo, out);
    }
}

// Round 23
// 29.742 us; speedup vs baseline: 1.0447x; 1.0415x over previous
//
#include <hip/hip_runtime.h>

#define NN 160      // nodes
#define BB 128      // batch
#define HH 256      // hidden
#define EE 5120     // edges
#define ST 128      // state dim
#define AC 32       // action dim
#define IH 80       // i-half rows

typedef __attribute__((ext_vector_type(8))) short short8;
typedef __attribute__((ext_vector_type(4))) short bf16x4;
typedef unsigned short us;
typedef __attribute__((ext_vector_type(4))) float f32x4;

__device__ inline us f2b(float f) {
    unsigned u = __builtin_bit_cast(unsigned, f);
    unsigned r = (u + 0x7FFFu + ((u >> 16) & 1u)) >> 16;
    return (us)r;
}
__device__ inline float b2f(us h) {
    return __builtin_bit_cast(float, (unsigned)h << 16);
}

// ---------- K1: graph rows + Pb/Mb (int-exact) + weight transposes + out init ----------
__global__ __launch_bounds__(256)
void k_pre(const int* __restrict__ ei, const float* __restrict__ W1,
           const float* __restrict__ W2, const float* __restrict__ state,
           const float* __restrict__ bo, us* __restrict__ Pb,
           us* __restrict__ Mb, us* __restrict__ W1t, us* __restrict__ W2t,
           float* __restrict__ out)
{
    const int bx = blockIdx.x, tid = threadIdx.x;
    if (bx < NN) {
        __shared__ int crow[NN];
        __shared__ unsigned abit[NN * NN / 32];   // 3.2 KB
        __shared__ float invdeg;
        if (tid < NN) crow[tid] = 0;
        for (int i = tid; i < NN * NN / 32; i += 256) abit[i] = 0;
        __syncthreads();
        for (int e = tid; e < EE; e += 256) {
            int s = ei[e], d = ei[EE + e];
            int p = d * NN + s;
            atomicOr(&abit[p >> 5], 1u << (p & 31));
            if (d == bx) atomicAdd(&crow[s], 1);
        }
        if (tid < NN) {
            int p = tid * NN + tid;
            atomicOr(&abit[p >> 5], 1u << (p & 31));
        }
        __syncthreads();
        if (tid == 0) {
            int dg = 0;
            for (int j = 0; j < NN; j++) dg += crow[j];
            invdeg = 1.0f / (float)(dg < 1 ? 1 : dg);
        }
        __syncthreads();
        if (tid < NN) {
            int s = 0;
            for (int k = 0; k < NN; k++) {
                int p = k * NN + tid;
                if (abit[p >> 5] & (1u << (p & 31))) s += crow[k];
            }
            Pb[bx * NN + tid] = f2b((float)s * invdeg);
            Mb[bx * NN + tid] = f2b((float)crow[tid] * invdeg);
        }
    } else if (bx < NN + 160) {                   // W1t: 256x160
        int idx = (bx - NN) * 256 + tid;
        int n = idx / NN, k = idx - n * NN;
        W1t[idx] = f2b(W1[k * HH + n]);
    } else if (bx < NN + 160 + 256) {             // W2t: 256x256
        int idx = (bx - NN - 160) * 256 + tid;
        int n = idx >> 8, k = idx & 255;
        W2t[idx] = f2b(W2[k * HH + n]);
    } else {                                      // out init: 128x128
        int idx = (bx - NN - 160 - 256) * 256 + tid;
        out[idx] = state[idx] + bo[idx & 127];
    }
}

// ---------- K2: 256 blocks = (i-half, batch), 1024 threads (16 waves) ----------
// Flattened LDS: no live-region overlap -> B5 deleted (7 barriers).
//  h1s @0      [256][168] = 43008 sh   (G1 out / G2 in)
//  Mbs @43008  [80][168]  = 13440 sh   (G2 B; overlays dead-Ys head)
//  ts  @56448  [80][264]  = 21120 sh   (G2 out / G3 in; disjoint from live)
//  pp  @77568  [4][256]f32 = 2048 sh   -> total 79616 sh = 159232 B
//  Ys  @43008  [160][168] = 26880 sh   (phase-1 only; dies at B3)
//  pts @56448  [8][128]f32             (after B-pp; ts dead)
__global__ __launch_bounds__(1024, 4)
void k_mega(const us* __restrict__ Pb, const float* __restrict__ state,
            const float* __restrict__ action, const us* __restrict__ W1t,
            const float* __restrict__ b1, const us* __restrict__ Mb,
            const us* __restrict__ W2t, const float* __restrict__ b2,
            const float* __restrict__ Wo, float* __restrict__ out)
{
    __shared__ __align__(16) us SH[79616];        // 159232 B
    __shared__ float xb[NN];
    us* h1s = SH;
    us* Mbs = SH + 43008;
    us* ts  = SH + 56448;
    us* Ys  = SH + 43008;             // phase-1 overlay (dead after B3)
    float* pp  = (float*)&SH[77568];  // [4][256] f32
    float* pts = (float*)&SH[56448];  // [8][128] f32 (over dead ts)

    const int ihalf = blockIdx.x, b = blockIdx.y, i_base = ihalf * IH;
    const int tid = threadIdx.x, lane = tid & 63, w = tid >> 6;  // 16 waves
    const int rl = lane & 15, kq = lane >> 4;

    if (tid < NN) xb[tid] = (tid < ST) ? state[b * ST + tid]
                                       : action[b * AC + (tid - ST)];
    __syncthreads();                                           // B1: xb

    // ---- stage Y = bf16(Pb*x) once ----
    for (int c = tid; c < 3200; c += 1024) {
        int r = c / 20, col = (c % 20) * 8;
        short8 p = *(const short8*)&Pb[r * NN + col];
        short8 y;
#pragma unroll
        for (int u = 0; u < 8; u++)
            y[u] = (short)f2b(b2f((us)p[u]) * xb[col + u]);
        *(short8*)&Ys[r * 168 + col] = y;
    }
    __syncthreads();                                           // B2: Ys

    // ---- T14: issue Mb chunk loads now (hide under G1) ----
    short8 mb0, mb1;
    {
        int c0 = tid;
        int r0 = c0 / 20, col0 = (c0 % 20) * 8;
        mb0 = *(const short8*)&Mb[(size_t)(i_base + r0) * NN + col0];
        if (tid < 576) {
            int c1 = tid + 1024;
            int r1 = c1 / 20, col1 = (c1 % 20) * 8;
            mb1 = *(const short8*)&Mb[(size_t)(i_base + r1) * NN + col1];
        }
    }

    // ======== G1, barrier-free, 32h x 80i per wave ========
    {
        const int wh = w & 7, wi = w >> 3;
        f32x4 acc1[5][2];
#pragma unroll
        for (int f = 0; f < 5; f++)
#pragma unroll
            for (int j = 0; j < 2; j++) acc1[f][j] = f32x4{0.f, 0.f, 0.f, 0.f};

        const us* w1r0 = W1t + (size_t)(wh * 32 + rl) * NN + kq * 8;
        const us* w1r1 = W1t + (size_t)(wh * 32 + 16 + rl) * NN + kq * 8;
#pragma unroll
        for (int kk = 0; kk < 5; kk++) {
            short8 bv0 = *(const short8*)&w1r0[kk * 32];
            short8 bv1 = *(const short8*)&w1r1[kk * 32];
            short8 af[5];
#pragma unroll
            for (int f = 0; f < 5; f++)
                af[f] = *(const short8*)&Ys[(wi * 80 + f * 16 + rl) * 168 + kk * 32 + kq * 8];
#pragma unroll
            for (int f = 0; f < 5; f++) {
                acc1[f][0] = __builtin_amdgcn_mfma_f32_16x16x32_bf16(
                    af[f], bv0, acc1[f][0], 0, 0, 0);
                acc1[f][1] = __builtin_amdgcn_mfma_f32_16x16x32_bf16(
                    af[f], bv1, acc1[f][1], 0, 0, 0);
            }
        }
        // epi -> h1s (disjoint from Ys) : col h, rows i
#pragma unroll
        for (int j = 0; j < 2; j++) {
            int h = wh * 32 + j * 16 + rl;
            float bias = b1[h];
#pragma unroll
            for (int f = 0; f < 5; f++) {
                int i0 = wi * 80 + f * 16 + kq * 4;
                bf16x4 v;
#pragma unroll
                for (int r = 0; r < 4; r++) {
                    float t = acc1[f][j][r] + bias;
                    v[r] = (short)f2b(t > 0.f ? t : 0.f);
                }
                *(bf16x4*)&h1s[h * 168 + i0] = v;
            }
        }
    }
    __syncthreads();                        // B3: h1s complete; Ys dead

    // ---- write pre-loaded Mb chunks (overlays dead Ys head) ----
    {
        int c0 = tid;
        int r0 = c0 / 20, col0 = (c0 % 20) * 8;
        *(short8*)&Mbs[r0 * 168 + col0] = mb0;
        if (tid < 576) {
            int c1 = tid + 1024;
            int r1 = c1 / 20, col1 = (c1 % 20) * 8;
            *(short8*)&Mbs[r1 * 168 + col1] = mb1;
        }
    }
    __syncthreads();                        // B4: Mbs ready

    // ======== G2 MFMAs + epilogue, barrier-free ========
    // ts region is disjoint from h1s AND Mbs -> no barrier between MFMAs and epi
    {
        f32x4 acc2[5];
#pragma unroll
        for (int j = 0; j < 5; j++) acc2[j] = f32x4{0.f, 0.f, 0.f, 0.f};
#pragma unroll
        for (int kk = 0; kk < 5; kk++) {
            short8 a = *(const short8*)&h1s[(w * 16 + rl) * 168 + kk * 32 + kq * 8];
            short8 bfv[5];
#pragma unroll
            for (int j = 0; j < 5; j++)
                bfv[j] = *(const short8*)&Mbs[(j * 16 + rl) * 168 + kk * 32 + kq * 8];
#pragma unroll
            for (int j = 0; j < 5; j++)
                acc2[j] = __builtin_amdgcn_mfma_f32_16x16x32_bf16(
                    a, bfv[j], acc2[j], 0, 0, 0);
        }
        // epi: D[h][i']: 4 consec h per reg-quad -> packed ts[i'][h0..3]
        int h0 = w * 16 + kq * 4;
#pragma unroll
        for (int j = 0; j < 5; j++) {
            int ip = j * 16 + rl;
            bf16x4 v;
#pragma unroll
            for (int r = 0; r < 4; r++)
                v[r] = (short)f2b(acc2[j][r]);
            *(bf16x4*)&ts[ip * 264 + h0] = v;
        }
    }
    __syncthreads();                        // B5: ts ready

    // ======== G3, barrier-free: A=ts (LDS), B=W2t (global, 1x) ========
    f32x4 acc3[5];
#pragma unroll
    for (int f = 0; f < 5; f++) acc3[f] = f32x4{0.f, 0.f, 0.f, 0.f};
    {
        const us* w2row = W2t + (size_t)(w * 16 + rl) * HH + kq * 8;
#pragma unroll
        for (int kk = 0; kk < 8; kk++) {
            short8 bv = *(const short8*)&w2row[kk * 32];
            short8 af[5];
#pragma unroll
            for (int f = 0; f < 5; f++)
                af[f] = *(const short8*)&ts[(f * 16 + rl) * 264 + kk * 32 + kq * 8];
#pragma unroll
            for (int f = 0; f < 5; f++)
                acc3[f] = __builtin_amdgcn_mfma_f32_16x16x32_bf16(
                    af[f], bv, acc3[f], 0, 0, 0);
        }
    }

    // ---- epi: bias+relu, in-lane pool over 20 i'-rows, slot by kq ----
    // pp @77568 disjoint from ts -> safe to write while others still read ts
    {
        int h = w * 16 + rl;
        float bias = b2[h];
        float s = 0.f;
#pragma unroll
        for (int f = 0; f < 5; f++)
#pragma unroll
            for (int r = 0; r < 4; r++) {
                float v = acc3[f][r] + bias;
                s += v > 0.f ? v : 0.f;
            }
        pp[kq * HH + h] = s;
    }
    __syncthreads();                        // B6: pp done; ts dead
    // ---- head partial: out[b][s] += (sum_h ph[h]*Wo[h][s]) / NN ----
    {
        const int q8 = tid >> 7, s128 = tid & 127;   // 8 h-chunks of 32
        float part = 0.f;
        for (int hx = q8 * 32; hx < q8 * 32 + 32; hx++) {
            float ph = pp[0 * HH + hx] + pp[1 * HH + hx] +
                       pp[2 * HH + hx] + pp[3 * HH + hx];
            part += ph * Wo[hx * ST + s128];
        }
        pts[q8 * ST + s128] = part;         // over dead ts
        __syncthreads();                    // B7: pts done
        if (tid < ST) {
            float o = 0.f;
#pragma unroll
            for (int qq = 0; qq < 8; qq++) o += pts[qq * ST + tid];
            atomicAdd(&out[b * ST + tid], o * (1.0f / NN));
        }
    }
}

extern "C" void kernel_launch(void* const* d_in, const int* in_sizes, int n_in,
                              void* d_out, int out_size, void* d_ws, size_t ws_size,
                              hipStream_t stream) {
    const float* state  = (const float*)d_in[0];
    const float* action = (const float*)d_in[1];
    const int*   ei     = (const int*)d_in[2];
    const float* W1     = (const float*)d_in[3];
    const float* b1     = (const float*)d_in[4];
    const float* W2     = (const float*)d_in[5];
    const float* b2     = (const float*)d_in[6];
    const float* Wo     = (const float*)d_in[7];
    const float* bo     = (const float*)d_in[8];
    float* out = (float*)d_out;

    char* ws = (char*)d_ws;
    size_t off = 0;
    auto alloc = [&](size_t bytes) {
        void* p = ws + off;
        off += (bytes + 255) & ~(size_t)255;
        return p;
    };
    us* Pb  = (us*)alloc(NN * NN * 2);
    us* Mb  = (us*)alloc(NN * NN * 2);
    us* W1t = (us*)alloc((size_t)HH * NN * 2);
    us* W2t = (us*)alloc((size_t)HH * HH * 2);

    // 160 graph rows + 160 W1t blocks + 256 W2t blocks + 64 out-init blocks
    k_pre<<<NN + 160 + 256 + 64, 256, 0, stream>>>(ei, W1, W2, state, bo,
                                                   Pb, Mb, W1t, W2t, out);
    {
        dim3 g(2, BB);   // (i-half, batch) = 256 blocks
        k_mega<<<g, 1024, 0, stream>>>(Pb, state, action, W1t, b1, Mb, W2t, b2,
                                       Wo, out);
    }
}